// Round 8
// baseline (870.505 us; speedup 1.0000x reference)
//
#include <hip/hip_runtime.h>
#include <hip/hip_bf16.h>

#define N_NODES 50000
#define N_EDGES 800000
#define M_PAD 50048  // 391 * 128

typedef __attribute__((ext_vector_type(8))) short short8;
typedef __attribute__((ext_vector_type(4))) float float4_;

#define GLOAD_LDS(g, l) __builtin_amdgcn_global_load_lds( \
    (const __attribute__((address_space(1))) void*)(g),   \
    (__attribute__((address_space(3))) void*)(l), 16, 0, 0)

__device__ __forceinline__ unsigned short f2bf(float f) {
    unsigned int u = __float_as_uint(f);
    unsigned int r = (u + 0x7FFFu + ((u >> 16) & 1u)) >> 16;
    return (unsigned short)r;
}
__device__ __forceinline__ float bf2f(unsigned short h) {
    return __uint_as_float(((unsigned int)h) << 16);
}

// ---------------- degree + CSR count (fused single pass) ----------------

__global__ __launch_bounds__(256) void degcnt_kernel(const int* __restrict__ dst,
                                                     const float* __restrict__ ew,
                                                     float* __restrict__ deg,
                                                     int* __restrict__ cnt, int E) {
    int e = blockIdx.x * blockDim.x + threadIdx.x;
    if (e < E) {
        int d = dst[e];
        atomicAdd(&deg[d], ew[e]);
        atomicAdd(&cnt[d], 1);
    }
}

__global__ __launch_bounds__(256) void dinv_kernel(float* __restrict__ deg, int n) {
    int i = blockIdx.x * blockDim.x + threadIdx.x;
    if (i < n) deg[i] = rsqrtf(deg[i] + 1.0f);
}

// ---------------- CSR build ----------------

__global__ __launch_bounds__(512) void scan_block_kernel(const int* __restrict__ cnt,
                                                         int* __restrict__ rowptr,
                                                         int* __restrict__ bsums, int n) {
    __shared__ int s[512];
    int t = threadIdx.x;
    int i = blockIdx.x * 512 + t;
    s[t] = (i < n) ? cnt[i] : 0;
    __syncthreads();
    for (int off = 1; off < 512; off <<= 1) {
        int v = (t >= off) ? s[t - off] : 0;
        __syncthreads();
        s[t] += v;
        __syncthreads();
    }
    if (i < n) rowptr[i + 1] = s[t];
    if (t == 511) bsums[blockIdx.x] = s[511];
}

__global__ void scan_sums_kernel(int* bsums, int nb) {
    if (threadIdx.x == 0 && blockIdx.x == 0) {
        int run = 0;
        for (int i = 0; i < nb; ++i) { int v = bsums[i]; bsums[i] = run; run += v; }
    }
}

__global__ __launch_bounds__(512) void scan_add_kernel(int* __restrict__ rowptr,
                                                       const int* __restrict__ bsums, int n) {
    int i = blockIdx.x * 512 + threadIdx.x;
    if (i < n) rowptr[i + 1] += bsums[blockIdx.x];
    if (i == 0) rowptr[0] = 0;
}

__global__ __launch_bounds__(256) void fill_kernel(const int* __restrict__ src,
                                                   const int* __restrict__ dst,
                                                   const float* __restrict__ ew,
                                                   const float* __restrict__ dinv,
                                                   int* __restrict__ cursor,
                                                   int* __restrict__ col,
                                                   float* __restrict__ val, int E) {
    int e = blockIdx.x * blockDim.x + threadIdx.x;
    if (e >= E) return;
    int d = dst[e];
    int s = src[e];
    int pos = atomicAdd(&cursor[d], 1);
    col[pos] = s;
    val[pos] = dinv[s] * ew[e];
}

// ---------------- weight transpose + split:  W[K][N] f32 -> Th/Tl [N][K] bf16 ----------------

__global__ __launch_bounds__(256) void wsplit_kernel(const float* __restrict__ Wm,
                                                     unsigned short* __restrict__ Th,
                                                     unsigned short* __restrict__ Tl,
                                                     int K, int N) {
    int idx = blockIdx.x * blockDim.x + threadIdx.x;  // idx = n*K + k (write-coalesced)
    if (idx >= K * N) return;
    int n = idx / K, k = idx - n * K;
    float v = Wm[(size_t)k * N + n];
    unsigned short hi = f2bf(v);
    float res = v - bf2f(hi);
    Th[idx] = hi;
    Tl[idx] = f2bf(res);
}

// ---------------- XCD-sharded CSR gather aggregation ----------------
// Feature dim split into 8 column slices; slice = blockIdx.x & 7 so each slice
// pins to one XCD (blockIdx round-robins XCDs) -> per-XCD L2 working set /8.
// Per edge: LPE lanes read a contiguous SC*4-byte slice of the source row;
// EPW edges per wave step; slot partials combined via shfl_xor tree.

template <int C, bool BIAS, bool RELU, bool SPLIT>
__global__ __launch_bounds__(256) void gather_shard(const float* __restrict__ t,
                                                    const int* __restrict__ rowptr,
                                                    const int* __restrict__ col,
                                                    const float* __restrict__ val,
                                                    const float* __restrict__ dinv,
                                                    const float* __restrict__ bias,
                                                    float* __restrict__ outf,
                                                    unsigned short* __restrict__ oh,
                                                    unsigned short* __restrict__ ol, int n) {
    constexpr int SC = C / 8;      // cols per slice (32 or 16)
    constexpr int LPE = SC / 4;    // lanes per edge (8 or 4)
    constexpr int EPW = 64 / LPE;  // edges per wave step (8 or 16)
    constexpr int U = 2;           // unroll depth
    int slice = blockIdx.x & 7;
    int nodeblk = blockIdx.x >> 3;
    int wave = threadIdx.x >> 6, lane = threadIdx.x & 63;
    int slot = lane / LPE;
    int li = lane % LPE;
    int colofs = slice * SC + li * 4;

    int node = nodeblk * 4 + wave;
    if (node >= n) return;

    int p0 = rowptr[node], p1 = rowptr[node + 1];
    float4 acc = {0.f, 0.f, 0.f, 0.f};
    for (int pb = p0; pb < p1; pb += U * EPW) {
        float a[U];
        float4 v[U];
#pragma unroll
        for (int u = 0; u < U; ++u) {
            int pe = pb + u * EPW + slot;
            int pec = min(pe, p1 - 1);          // clamped: unconditional loads
            int s = col[pec];
            float av = val[pec];
            a[u] = (pe < p1) ? av : 0.f;        // mask coefficient only
            v[u] = *(const float4*)(t + (size_t)s * C + colofs);
        }
#pragma unroll
        for (int u = 0; u < U; ++u) {
            acc.x += a[u] * v[u].x;
            acc.y += a[u] * v[u].y;
            acc.z += a[u] * v[u].z;
            acc.w += a[u] * v[u].w;
        }
    }
    // combine edge-slot partials: tree over the slot dimension
#pragma unroll
    for (int m = LPE; m <= 32; m <<= 1) {
        acc.x += __shfl_xor(acc.x, m);
        acc.y += __shfl_xor(acc.y, m);
        acc.z += __shfl_xor(acc.z, m);
        acc.w += __shfl_xor(acc.w, m);
    }
    if (slot == 0) {
        float di = dinv[node];
        float s2 = di * di;
        float4 tv = *(const float4*)(t + (size_t)node * C + colofs);
        float4 r;
        r.x = di * acc.x + s2 * tv.x;
        r.y = di * acc.y + s2 * tv.y;
        r.z = di * acc.z + s2 * tv.z;
        r.w = di * acc.w + s2 * tv.w;
        if (BIAS) {
            float4 b4 = *(const float4*)(bias + colofs);
            r.x += b4.x; r.y += b4.y; r.z += b4.z; r.w += b4.w;
        }
        if (RELU) {
            r.x = fmaxf(r.x, 0.f); r.y = fmaxf(r.y, 0.f);
            r.z = fmaxf(r.z, 0.f); r.w = fmaxf(r.w, 0.f);
        }
        size_t base = (size_t)node * C + colofs;
        if (SPLIT) {
            float rv[4] = {r.x, r.y, r.z, r.w};
            ushort4 h4, l4;
            unsigned short hs[4], lsx[4];
#pragma unroll
            for (int j = 0; j < 4; ++j) {
                unsigned short hi = f2bf(rv[j]);
                hs[j] = hi;
                lsx[j] = f2bf(rv[j] - bf2f(hi));
            }
            h4.x = hs[0]; h4.y = hs[1]; h4.z = hs[2]; h4.w = hs[3];
            l4.x = lsx[0]; l4.y = lsx[1]; l4.z = lsx[2]; l4.w = lsx[3];
            *(ushort4*)(oh + base) = h4;
            *(ushort4*)(ol + base) = l4;
        } else {
            *(float4*)(outf + base) = r;
        }
    }
}

// ---------------- split-bf16 MFMA GEMM ----------------
// C[M_PAD][N] = A[M_PAD][K] * B[K][N], A given as hi/lo bf16 planes [M_PAD][K],
// B given as transposed hi/lo planes [N][K]. 3-pass split: Ah*Bh + Ah*Bl + Al*Bh.
// Block: 256 thr (4 waves), tile 128(M) x 128(N), BK=64. Wave tile 64x64.
// OUTMODE 0: Cf = acc (f32).  OUTMODE 1: split(relu(acc + bias)) -> Ch/Cl planes.

template <int OUTMODE>
__global__ __launch_bounds__(256, 2) void mfma_gemm(const unsigned short* __restrict__ Ah,
                                                    const unsigned short* __restrict__ Al,
                                                    const unsigned short* __restrict__ Bh,
                                                    const unsigned short* __restrict__ Bl,
                                                    const float* __restrict__ bias,
                                                    float* __restrict__ Cf,
                                                    unsigned short* __restrict__ Ch,
                                                    unsigned short* __restrict__ Cl,
                                                    int K, int N) {
    __shared__ unsigned short sAh[128 * 64];
    __shared__ unsigned short sAl[128 * 64];
    __shared__ unsigned short sBh[128 * 64];
    __shared__ unsigned short sBl[128 * 64];

    int tid = threadIdx.x;
    int lane = tid & 63, w = tid >> 6;
    int m0 = blockIdx.x * 128, n0 = blockIdx.y * 128;

    // staging assignment: wave w handles one plane
    const unsigned short* gsrc = (w == 0) ? Ah : (w == 1) ? Al : (w == 2) ? Bh : Bl;
    unsigned short* sbase = (w == 0) ? sAh : (w == 1) ? sAl : (w == 2) ? sBh : sBl;
    int grow0 = ((w < 2) ? m0 : n0) + (lane >> 3);
    int gcol = ((lane & 7) ^ ((lane >> 3) & 7)) * 8;  // inverse-swizzled source column
    const unsigned short* gptr0 = gsrc + (size_t)grow0 * K + gcol;

    float4_ acc[4][4] = {};

    int wm = (w >> 1) * 64, wn = (w & 1) * 64;
    int lr = lane & 15, lg = lane >> 4;

    for (int k0 = 0; k0 < K; k0 += 64) {
        const unsigned short* gp = gptr0 + k0;
#pragma unroll
        for (int q = 0; q < 16; ++q)
            GLOAD_LDS(gp + (size_t)(8 * q) * K, sbase + q * 512);
        __syncthreads();

#pragma unroll
        for (int ks = 0; ks < 2; ++ks) {
            short8 ahf[4], alf[4], bhf[4], blf[4];
#pragma unroll
            for (int f = 0; f < 4; ++f) {
                int ra = wm + f * 16 + lr;
                int sa = (((ks << 2) | lg) ^ (ra & 7)) * 16;
                ahf[f] = *(const short8*)((const char*)sAh + ra * 128 + sa);
                alf[f] = *(const short8*)((const char*)sAl + ra * 128 + sa);
                int rb = wn + f * 16 + lr;
                int sb = (((ks << 2) | lg) ^ (rb & 7)) * 16;
                bhf[f] = *(const short8*)((const char*)sBh + rb * 128 + sb);
                blf[f] = *(const short8*)((const char*)sBl + rb * 128 + sb);
            }
#pragma unroll
            for (int i = 0; i < 4; ++i)
#pragma unroll
                for (int j = 0; j < 4; ++j) {
                    acc[i][j] = __builtin_amdgcn_mfma_f32_16x16x32_bf16(ahf[i], bhf[j], acc[i][j], 0, 0, 0);
                    acc[i][j] = __builtin_amdgcn_mfma_f32_16x16x32_bf16(ahf[i], blf[j], acc[i][j], 0, 0, 0);
                    acc[i][j] = __builtin_amdgcn_mfma_f32_16x16x32_bf16(alf[i], bhf[j], acc[i][j], 0, 0, 0);
                }
        }
        __syncthreads();
    }

    // epilogue: C row = m0+wm+i*16+lg*4+r, col = n0+wn+j*16+lr  (m89-verified layout)
#pragma unroll
    for (int i = 0; i < 4; ++i) {
        int row0 = m0 + wm + i * 16 + lg * 4;
#pragma unroll
        for (int j = 0; j < 4; ++j) {
            int colg = n0 + wn + j * 16 + lr;
            float b = (OUTMODE == 1) ? bias[colg] : 0.f;
#pragma unroll
            for (int r = 0; r < 4; ++r) {
                float v = acc[i][j][r] + b;
                size_t idx = (size_t)(row0 + r) * N + colg;
                if (OUTMODE == 1) {
                    v = fmaxf(v, 0.f);
                    unsigned short hi = f2bf(v);
                    float res = v - bf2f(hi);
                    Ch[idx] = hi;
                    Cl[idx] = f2bf(res);
                } else {
                    Cf[idx] = v;
                }
            }
        }
    }
}

// ---------------- fused MLP head + softmax ----------------

__global__ __launch_bounds__(256) void mlp_kernel(const float* __restrict__ h,
                                                  const float* __restrict__ W1, const float* __restrict__ b1,
                                                  const float* __restrict__ W2, const float* __restrict__ b2,
                                                  const float* __restrict__ W3, const float* __restrict__ b3,
                                                  float* __restrict__ out, int n) {
    __shared__ float W1s[128 * 64];
    __shared__ float W2s[64 * 32];
    __shared__ float W3s[32 * 40];
    __shared__ float b1s[64], b2s[32], b3s[40];
    __shared__ float hs[4][128];
    __shared__ float h1s[4][64];
    __shared__ float h2s[4][32];
    __shared__ float ls[4][40];
    __shared__ float es[4][40];

    int tid = threadIdx.x;
    for (int i = tid; i < 128 * 64; i += 256) W1s[i] = W1[i];
    for (int i = tid; i < 64 * 32; i += 256) W2s[i] = W2[i];
    for (int i = tid; i < 32 * 40; i += 256) W3s[i] = W3[i];
    if (tid < 64) b1s[tid] = b1[tid];
    if (tid < 32) b2s[tid] = b2[tid];
    if (tid < 40) b3s[tid] = b3[tid];
    __syncthreads();

    int wave = tid >> 6, lane = tid & 63;

    for (int base = blockIdx.x * 4; base < n; base += gridDim.x * 4) {
        int node = base + wave;
        if (node < n) {
            hs[wave][lane]      = fmaxf(h[(size_t)node * 128 + lane], 0.f);
            hs[wave][lane + 64] = fmaxf(h[(size_t)node * 128 + lane + 64], 0.f);
        }
        __syncthreads();
        {
            float acc = b1s[lane];
#pragma unroll 8
            for (int k = 0; k < 128; ++k) acc += hs[wave][k] * W1s[k * 64 + lane];
            h1s[wave][lane] = fmaxf(acc, 0.f);
        }
        __syncthreads();
        if (lane < 32) {
            float acc = b2s[lane];
#pragma unroll 8
            for (int k = 0; k < 64; ++k) acc += h1s[wave][k] * W2s[k * 32 + lane];
            h2s[wave][lane] = fmaxf(acc, 0.f);
        }
        __syncthreads();
        if (lane < 40) {
            float acc = b3s[lane];
#pragma unroll 8
            for (int k = 0; k < 32; ++k) acc += h2s[wave][k] * W3s[k * 40 + lane];
            ls[wave][lane] = acc;
        }
        __syncthreads();
        float e = 0.f;
        if (lane < 40) {
            float m = -1e30f;
            for (int j = 0; j < 40; ++j) m = fmaxf(m, ls[wave][j]);
            e = expf(ls[wave][lane] - m);
            es[wave][lane] = e;
        }
        __syncthreads();
        if (node < n && lane < 40) {
            float s = 0.f;
            for (int j = 0; j < 40; ++j) s += es[wave][j];
            out[(size_t)node * 40 + lane] = e / s;
        }
        __syncthreads();
    }
}

// ---------------- launcher ----------------

extern "C" void kernel_launch(void* const* d_in, const int* in_sizes, int n_in,
                              void* d_out, int out_size, void* d_ws, size_t ws_size,
                              hipStream_t stream) {
    const float* x   = (const float*)d_in[0];
    const int*   ei  = (const int*)d_in[1];
    const float* ew  = (const float*)d_in[2];
    const float* W1  = (const float*)d_in[3];
    const float* b1  = (const float*)d_in[4];
    const float* W2  = (const float*)d_in[5];
    const float* b2  = (const float*)d_in[6];
    const float* W3  = (const float*)d_in[7];
    const float* b3  = (const float*)d_in[8];
    const float* L1w = (const float*)d_in[9];
    const float* L1b = (const float*)d_in[10];
    const float* L2w = (const float*)d_in[11];
    const float* L2b = (const float*)d_in[12];
    const float* L3w = (const float*)d_in[13];
    const float* L3b = (const float*)d_in[14];
    float* out = (float*)d_out;

    const int n = N_NODES, E = N_EDGES;
    const int* src = ei;
    const int* dst = ei + E;

    // ---- workspace layout (bytes) ----
    char* wsb = (char*)d_ws;
    size_t off = 0;
    auto alloc = [&](size_t bytes) -> char* {
        char* p = wsb + off;
        off += (bytes + 255) & ~(size_t)255;
        return p;
    };
    float* dinv   = (float*)alloc(N_NODES * 4);
    int* rowptr   = (int*)alloc((N_NODES + 1) * 4);
    int* cursor   = (int*)alloc(N_NODES * 4);
    int* colb     = (int*)alloc((size_t)N_EDGES * 4);
    float* val    = (float*)alloc((size_t)N_EDGES * 4);
    int* bsums    = (int*)alloc(256 * 4);
    unsigned short* W1th = (unsigned short*)alloc(512 * 128 * 2);
    unsigned short* W1tl = (unsigned short*)alloc(512 * 128 * 2);
    unsigned short* W2th = (unsigned short*)alloc(256 * 512 * 2);
    unsigned short* W2tl = (unsigned short*)alloc(256 * 512 * 2);
    unsigned short* W3th = (unsigned short*)alloc(128 * 256 * 2);
    unsigned short* W3tl = (unsigned short*)alloc(128 * 256 * 2);
    unsigned short* aggXh = (unsigned short*)alloc((size_t)M_PAD * 128 * 2);  // pool A
    unsigned short* aggXl = (unsigned short*)alloc((size_t)M_PAD * 128 * 2);
    unsigned short* h1h  = (unsigned short*)alloc((size_t)M_PAD * 512 * 2);   // pool B1
    unsigned short* h1l  = (unsigned short*)alloc((size_t)M_PAD * 512 * 2);   // pool B2
    float* t2     = (float*)alloc((size_t)M_PAD * 256 * 4);
    // aliases (lifetimes disjoint):
    unsigned short* agg2h = aggXh;                                   // aggX dead after GEMM L1 (25.6MB = both aggX planes)
    unsigned short* agg2l = (unsigned short*)h1h;                    // h1 dead after GEMM L2 (first half of h1h)
    float* t3   = (float*)((char*)h1h + (size_t)M_PAD * 256 * 2);    // second half of h1h
    float* agg3 = (float*)h1l;                                       // first 25.6MB of h1l

    const int nb = (n + 511) / 512;
    const int gshard = ((n + 3) / 4) * 8;  // sharded gather grid

    // deg + CSR count (one pass)
    hipMemsetAsync(dinv, 0, n * sizeof(float), stream);
    hipMemsetAsync(cursor, 0, n * sizeof(int), stream);
    degcnt_kernel<<<(E + 255) / 256, 256, 0, stream>>>(dst, ew, dinv, cursor, E);
    dinv_kernel<<<(n + 255) / 256, 256, 0, stream>>>(dinv, n);

    // weight transpose+split (independent, cheap)
    wsplit_kernel<<<(128 * 512 + 255) / 256, 256, 0, stream>>>(W1, W1th, W1tl, 128, 512);
    wsplit_kernel<<<(512 * 256 + 255) / 256, 256, 0, stream>>>(W2, W2th, W2tl, 512, 256);
    wsplit_kernel<<<(256 * 128 + 255) / 256, 256, 0, stream>>>(W3, W3th, W3tl, 256, 128);

    // CSR build (by dst)
    scan_block_kernel<<<nb, 512, 0, stream>>>(cursor, rowptr, bsums, n);
    scan_sums_kernel<<<1, 64, 0, stream>>>(bsums, nb);
    scan_add_kernel<<<nb, 512, 0, stream>>>(rowptr, bsums, n);
    hipMemcpyAsync(cursor, rowptr, n * sizeof(int), hipMemcpyDeviceToDevice, stream);
    fill_kernel<<<(E + 255) / 256, 256, 0, stream>>>(src, dst, ew, dinv, cursor, colb, val, E);

    // ----- layer 1: aggX = A_hat x (split) ; h1 = split(relu(aggX@W1 + b1))
    gather_shard<128, false, false, true><<<gshard, 256, 0, stream>>>(
        x, rowptr, colb, val, dinv, nullptr, nullptr, aggXh, aggXl, n);
    {
        dim3 g(M_PAD / 128, 512 / 128);
        mfma_gemm<1><<<g, 256, 0, stream>>>(aggXh, aggXl, W1th, W1tl, b1, nullptr, h1h, h1l, 128, 512);
    }
    // ----- layer 2: t2 = h1 @ W2 (f32) ; agg2 = split(relu(A_hat t2 + b2))
    {
        dim3 g(M_PAD / 128, 256 / 128);
        mfma_gemm<0><<<g, 256, 0, stream>>>(h1h, h1l, W2th, W2tl, nullptr, t2, nullptr, nullptr, 512, 256);
    }
    gather_shard<256, true, true, true><<<gshard, 256, 0, stream>>>(
        t2, rowptr, colb, val, dinv, b2, nullptr, agg2h, agg2l, n);
    // ----- layer 3: t3 = relu(agg2) @ W3 (f32) ; agg3 = A_hat t3 + b3 (f32)
    {
        dim3 g(M_PAD / 128, 128 / 128);
        mfma_gemm<0><<<g, 256, 0, stream>>>(agg2h, agg2l, W3th, W3tl, nullptr, t3, nullptr, nullptr, 256, 128);
    }
    gather_shard<128, true, false, false><<<gshard, 256, 0, stream>>>(
        t3, rowptr, colb, val, dinv, b3, agg3, nullptr, nullptr, n);
    // ----- MLP head + softmax
    mlp_kernel<<<1024, 256, 0, stream>>>(agg3, L1w, L1b, L2w, L2b, L3w, L3b, out, n);
}

// Round 9
// 805.380 us; speedup vs baseline: 1.0809x; 1.0809x over previous
//
#include <hip/hip_runtime.h>
#include <hip/hip_bf16.h>

#define N_NODES 50000
#define N_EDGES 800000
#define M_PAD 50048  // 391 * 128

typedef __attribute__((ext_vector_type(8))) short short8;
typedef __attribute__((ext_vector_type(4))) float float4_;

#define GLOAD_LDS(g, l) __builtin_amdgcn_global_load_lds( \
    (const __attribute__((address_space(1))) void*)(g),   \
    (__attribute__((address_space(3))) void*)(l), 16, 0, 0)

__device__ __forceinline__ unsigned short f2bf(float f) {
    unsigned int u = __float_as_uint(f);
    unsigned int r = (u + 0x7FFFu + ((u >> 16) & 1u)) >> 16;
    return (unsigned short)r;
}
__device__ __forceinline__ float bf2f(unsigned short h) {
    return __uint_as_float(((unsigned int)h) << 16);
}

// ---------------- degree + CSR count (fused single pass) ----------------

__global__ __launch_bounds__(256) void degcnt_kernel(const int* __restrict__ dst,
                                                     const float* __restrict__ ew,
                                                     float* __restrict__ deg,
                                                     int* __restrict__ cnt, int E) {
    int e = blockIdx.x * blockDim.x + threadIdx.x;
    if (e < E) {
        int d = dst[e];
        atomicAdd(&deg[d], ew[e]);
        atomicAdd(&cnt[d], 1);
    }
}

__global__ __launch_bounds__(256) void dinv_kernel(float* __restrict__ deg, int n) {
    int i = blockIdx.x * blockDim.x + threadIdx.x;
    if (i < n) deg[i] = rsqrtf(deg[i] + 1.0f);
}

// ---------------- CSR build ----------------

__global__ __launch_bounds__(512) void scan_block_kernel(const int* __restrict__ cnt,
                                                         int* __restrict__ rowptr,
                                                         int* __restrict__ bsums, int n) {
    __shared__ int s[512];
    int t = threadIdx.x;
    int i = blockIdx.x * 512 + t;
    s[t] = (i < n) ? cnt[i] : 0;
    __syncthreads();
    for (int off = 1; off < 512; off <<= 1) {
        int v = (t >= off) ? s[t - off] : 0;
        __syncthreads();
        s[t] += v;
        __syncthreads();
    }
    if (i < n) rowptr[i + 1] = s[t];
    if (t == 511) bsums[blockIdx.x] = s[511];
}

__global__ void scan_sums_kernel(int* bsums, int nb) {
    if (threadIdx.x == 0 && blockIdx.x == 0) {
        int run = 0;
        for (int i = 0; i < nb; ++i) { int v = bsums[i]; bsums[i] = run; run += v; }
    }
}

__global__ __launch_bounds__(512) void scan_add_kernel(int* __restrict__ rowptr,
                                                       const int* __restrict__ bsums, int n) {
    int i = blockIdx.x * 512 + threadIdx.x;
    if (i < n) rowptr[i + 1] += bsums[blockIdx.x];
    if (i == 0) rowptr[0] = 0;
}

__global__ __launch_bounds__(256) void fill_kernel(const int* __restrict__ src,
                                                   const int* __restrict__ dst,
                                                   const float* __restrict__ ew,
                                                   const float* __restrict__ dinv,
                                                   int* __restrict__ cursor,
                                                   int* __restrict__ col,
                                                   float* __restrict__ val, int E) {
    int e = blockIdx.x * blockDim.x + threadIdx.x;
    if (e >= E) return;
    int d = dst[e];
    int s = src[e];
    int pos = atomicAdd(&cursor[d], 1);
    col[pos] = s;
    val[pos] = dinv[s] * ew[e];
}

// ---------------- weight transpose + split:  W[K][N] f32 -> Th/Tl [N][K] bf16 ----------------

__global__ __launch_bounds__(256) void wsplit_kernel(const float* __restrict__ Wm,
                                                     unsigned short* __restrict__ Th,
                                                     unsigned short* __restrict__ Tl,
                                                     int K, int N) {
    int idx = blockIdx.x * blockDim.x + threadIdx.x;  // idx = n*K + k (write-coalesced)
    if (idx >= K * N) return;
    int n = idx / K, k = idx - n * K;
    float v = Wm[(size_t)k * N + n];
    unsigned short hi = f2bf(v);
    float res = v - bf2f(hi);
    Th[idx] = hi;
    Tl[idx] = f2bf(res);
}

// ---------------- XCD-sharded CSR gather aggregation, v2 (node-loop) ----------------
// Feature dim split into 8 column slices; slice = blockIdx.x & 7 pins each slice
// to one XCD (consecutive blockIdx round-robin XCDs) -> per-XCD L2 working set /8.
// v2: grid-stride node loop amortizes prologue/epilogue over ~12 nodes per wave
// (R8 lesson: 1 node/wave was VALU/overhead-bound at avg degree 16).

template <int C, bool BIAS, bool RELU, bool SPLIT>
__global__ __launch_bounds__(256) void gather_shard(const float* __restrict__ t,
                                                    const int* __restrict__ rowptr,
                                                    const int* __restrict__ col,
                                                    const float* __restrict__ val,
                                                    const float* __restrict__ dinv,
                                                    const float* __restrict__ bias,
                                                    float* __restrict__ outf,
                                                    unsigned short* __restrict__ oh,
                                                    unsigned short* __restrict__ ol, int n) {
    constexpr int SC = C / 8;      // cols per slice (32 or 16)
    constexpr int LPE = SC / 4;    // lanes per edge (8 or 4)
    constexpr int EPW = 64 / LPE;  // edges per wave step (8 or 16)
    constexpr int U = 2;           // unroll depth
    int slice = blockIdx.x & 7;
    int nodeblk = blockIdx.x >> 3;
    int nstride = (gridDim.x >> 3) * 4;
    int wave = threadIdx.x >> 6, lane = threadIdx.x & 63;
    int slot = lane / LPE;
    int li = lane % LPE;
    int colofs = slice * SC + li * 4;
    const float* tb = t + colofs;   // hoisted column base

    float4 b4 = {0.f, 0.f, 0.f, 0.f};
    if (BIAS) b4 = *(const float4*)(bias + colofs);

    for (int node = nodeblk * 4 + wave; node < n; node += nstride) {
        int p0 = rowptr[node], p1 = rowptr[node + 1];
        float4 acc = {0.f, 0.f, 0.f, 0.f};
        for (int pb = p0; pb < p1; pb += U * EPW) {
            float a[U];
            float4 v[U];
#pragma unroll
            for (int u = 0; u < U; ++u) {
                int pe = pb + u * EPW + slot;
                int pec = min(pe, p1 - 1);          // clamped: unconditional loads
                int s = col[pec];
                float av = val[pec];
                a[u] = (pe < p1) ? av : 0.f;        // mask coefficient only
                v[u] = *(const float4*)(tb + (size_t)s * C);
            }
#pragma unroll
            for (int u = 0; u < U; ++u) {
                acc.x += a[u] * v[u].x;
                acc.y += a[u] * v[u].y;
                acc.z += a[u] * v[u].z;
                acc.w += a[u] * v[u].w;
            }
        }
        // combine edge-slot partials: tree over the slot dimension
#pragma unroll
        for (int m = LPE; m <= 32; m <<= 1) {
            acc.x += __shfl_xor(acc.x, m);
            acc.y += __shfl_xor(acc.y, m);
            acc.z += __shfl_xor(acc.z, m);
            acc.w += __shfl_xor(acc.w, m);
        }
        if (slot == 0) {
            float di = dinv[node];
            float s2 = di * di;
            float4 tv = *(const float4*)(tb + (size_t)node * C);
            float4 r;
            r.x = di * acc.x + s2 * tv.x + b4.x;
            r.y = di * acc.y + s2 * tv.y + b4.y;
            r.z = di * acc.z + s2 * tv.z + b4.z;
            r.w = di * acc.w + s2 * tv.w + b4.w;
            if (RELU) {
                r.x = fmaxf(r.x, 0.f); r.y = fmaxf(r.y, 0.f);
                r.z = fmaxf(r.z, 0.f); r.w = fmaxf(r.w, 0.f);
            }
            size_t base = (size_t)node * C + colofs;
            if (SPLIT) {
                float rv[4] = {r.x, r.y, r.z, r.w};
                ushort4 h4, l4;
                unsigned short hs[4], lsx[4];
#pragma unroll
                for (int j = 0; j < 4; ++j) {
                    unsigned short hi = f2bf(rv[j]);
                    hs[j] = hi;
                    lsx[j] = f2bf(rv[j] - bf2f(hi));
                }
                h4.x = hs[0]; h4.y = hs[1]; h4.z = hs[2]; h4.w = hs[3];
                l4.x = lsx[0]; l4.y = lsx[1]; l4.z = lsx[2]; l4.w = lsx[3];
                *(ushort4*)(oh + base) = h4;
                *(ushort4*)(ol + base) = l4;
            } else {
                *(float4*)(outf + base) = r;
            }
        }
    }
}

// ---------------- split-bf16 MFMA GEMM ----------------
// C[M_PAD][N] = A[M_PAD][K] * B[K][N], A given as hi/lo bf16 planes [M_PAD][K],
// B given as transposed hi/lo planes [N][K]. 3-pass split: Ah*Bh + Ah*Bl + Al*Bh.
// Block: 256 thr (4 waves), tile 128(M) x 128(N), BK=64. Wave tile 64x64.
// OUTMODE 0: Cf = acc (f32).  OUTMODE 1: split(relu(acc + bias)) -> Ch/Cl planes.

template <int OUTMODE>
__global__ __launch_bounds__(256, 2) void mfma_gemm(const unsigned short* __restrict__ Ah,
                                                    const unsigned short* __restrict__ Al,
                                                    const unsigned short* __restrict__ Bh,
                                                    const unsigned short* __restrict__ Bl,
                                                    const float* __restrict__ bias,
                                                    float* __restrict__ Cf,
                                                    unsigned short* __restrict__ Ch,
                                                    unsigned short* __restrict__ Cl,
                                                    int K, int N) {
    __shared__ unsigned short sAh[128 * 64];
    __shared__ unsigned short sAl[128 * 64];
    __shared__ unsigned short sBh[128 * 64];
    __shared__ unsigned short sBl[128 * 64];

    int tid = threadIdx.x;
    int lane = tid & 63, w = tid >> 6;
    int m0 = blockIdx.x * 128, n0 = blockIdx.y * 128;

    // staging assignment: wave w handles one plane
    const unsigned short* gsrc = (w == 0) ? Ah : (w == 1) ? Al : (w == 2) ? Bh : Bl;
    unsigned short* sbase = (w == 0) ? sAh : (w == 1) ? sAl : (w == 2) ? sBh : sBl;
    int grow0 = ((w < 2) ? m0 : n0) + (lane >> 3);
    int gcol = ((lane & 7) ^ ((lane >> 3) & 7)) * 8;  // inverse-swizzled source column
    const unsigned short* gptr0 = gsrc + (size_t)grow0 * K + gcol;

    float4_ acc[4][4] = {};

    int wm = (w >> 1) * 64, wn = (w & 1) * 64;
    int lr = lane & 15, lg = lane >> 4;

    for (int k0 = 0; k0 < K; k0 += 64) {
        const unsigned short* gp = gptr0 + k0;
#pragma unroll
        for (int q = 0; q < 16; ++q)
            GLOAD_LDS(gp + (size_t)(8 * q) * K, sbase + q * 512);
        __syncthreads();

#pragma unroll
        for (int ks = 0; ks < 2; ++ks) {
            short8 ahf[4], alf[4], bhf[4], blf[4];
#pragma unroll
            for (int f = 0; f < 4; ++f) {
                int ra = wm + f * 16 + lr;
                int sa = (((ks << 2) | lg) ^ (ra & 7)) * 16;
                ahf[f] = *(const short8*)((const char*)sAh + ra * 128 + sa);
                alf[f] = *(const short8*)((const char*)sAl + ra * 128 + sa);
                int rb = wn + f * 16 + lr;
                int sb = (((ks << 2) | lg) ^ (rb & 7)) * 16;
                bhf[f] = *(const short8*)((const char*)sBh + rb * 128 + sb);
                blf[f] = *(const short8*)((const char*)sBl + rb * 128 + sb);
            }
#pragma unroll
            for (int i = 0; i < 4; ++i)
#pragma unroll
                for (int j = 0; j < 4; ++j) {
                    acc[i][j] = __builtin_amdgcn_mfma_f32_16x16x32_bf16(ahf[i], bhf[j], acc[i][j], 0, 0, 0);
                    acc[i][j] = __builtin_amdgcn_mfma_f32_16x16x32_bf16(ahf[i], blf[j], acc[i][j], 0, 0, 0);
                    acc[i][j] = __builtin_amdgcn_mfma_f32_16x16x32_bf16(alf[i], bhf[j], acc[i][j], 0, 0, 0);
                }
        }
        __syncthreads();
    }

    // epilogue: C row = m0+wm+i*16+lg*4+r, col = n0+wn+j*16+lr  (m89-verified layout)
#pragma unroll
    for (int i = 0; i < 4; ++i) {
        int row0 = m0 + wm + i * 16 + lg * 4;
#pragma unroll
        for (int j = 0; j < 4; ++j) {
            int colg = n0 + wn + j * 16 + lr;
            float b = (OUTMODE == 1) ? bias[colg] : 0.f;
#pragma unroll
            for (int r = 0; r < 4; ++r) {
                float v = acc[i][j][r] + b;
                size_t idx = (size_t)(row0 + r) * N + colg;
                if (OUTMODE == 1) {
                    v = fmaxf(v, 0.f);
                    unsigned short hi = f2bf(v);
                    float res = v - bf2f(hi);
                    Ch[idx] = hi;
                    Cl[idx] = f2bf(res);
                } else {
                    Cf[idx] = v;
                }
            }
        }
    }
}

// ---------------- fused MLP head + softmax ----------------

__global__ __launch_bounds__(256) void mlp_kernel(const float* __restrict__ h,
                                                  const float* __restrict__ W1, const float* __restrict__ b1,
                                                  const float* __restrict__ W2, const float* __restrict__ b2,
                                                  const float* __restrict__ W3, const float* __restrict__ b3,
                                                  float* __restrict__ out, int n) {
    __shared__ float W1s[128 * 64];
    __shared__ float W2s[64 * 32];
    __shared__ float W3s[32 * 40];
    __shared__ float b1s[64], b2s[32], b3s[40];
    __shared__ float hs[4][128];
    __shared__ float h1s[4][64];
    __shared__ float h2s[4][32];
    __shared__ float ls[4][40];
    __shared__ float es[4][40];

    int tid = threadIdx.x;
    for (int i = tid; i < 128 * 64; i += 256) W1s[i] = W1[i];
    for (int i = tid; i < 64 * 32; i += 256) W2s[i] = W2[i];
    for (int i = tid; i < 32 * 40; i += 256) W3s[i] = W3[i];
    if (tid < 64) b1s[tid] = b1[tid];
    if (tid < 32) b2s[tid] = b2[tid];
    if (tid < 40) b3s[tid] = b3[tid];
    __syncthreads();

    int wave = tid >> 6, lane = tid & 63;

    for (int base = blockIdx.x * 4; base < n; base += gridDim.x * 4) {
        int node = base + wave;
        if (node < n) {
            hs[wave][lane]      = fmaxf(h[(size_t)node * 128 + lane], 0.f);
            hs[wave][lane + 64] = fmaxf(h[(size_t)node * 128 + lane + 64], 0.f);
        }
        __syncthreads();
        {
            float acc = b1s[lane];
#pragma unroll 8
            for (int k = 0; k < 128; ++k) acc += hs[wave][k] * W1s[k * 64 + lane];
            h1s[wave][lane] = fmaxf(acc, 0.f);
        }
        __syncthreads();
        if (lane < 32) {
            float acc = b2s[lane];
#pragma unroll 8
            for (int k = 0; k < 64; ++k) acc += h1s[wave][k] * W2s[k * 32 + lane];
            h2s[wave][lane] = fmaxf(acc, 0.f);
        }
        __syncthreads();
        if (lane < 40) {
            float acc = b3s[lane];
#pragma unroll 8
            for (int k = 0; k < 32; ++k) acc += h2s[wave][k] * W3s[k * 40 + lane];
            ls[wave][lane] = acc;
        }
        __syncthreads();
        float e = 0.f;
        if (lane < 40) {
            float m = -1e30f;
            for (int j = 0; j < 40; ++j) m = fmaxf(m, ls[wave][j]);
            e = expf(ls[wave][lane] - m);
            es[wave][lane] = e;
        }
        __syncthreads();
        if (node < n && lane < 40) {
            float s = 0.f;
            for (int j = 0; j < 40; ++j) s += es[wave][j];
            out[(size_t)node * 40 + lane] = e / s;
        }
        __syncthreads();
    }
}

// ---------------- launcher ----------------

extern "C" void kernel_launch(void* const* d_in, const int* in_sizes, int n_in,
                              void* d_out, int out_size, void* d_ws, size_t ws_size,
                              hipStream_t stream) {
    const float* x   = (const float*)d_in[0];
    const int*   ei  = (const int*)d_in[1];
    const float* ew  = (const float*)d_in[2];
    const float* W1  = (const float*)d_in[3];
    const float* b1  = (const float*)d_in[4];
    const float* W2  = (const float*)d_in[5];
    const float* b2  = (const float*)d_in[6];
    const float* W3  = (const float*)d_in[7];
    const float* b3  = (const float*)d_in[8];
    const float* L1w = (const float*)d_in[9];
    const float* L1b = (const float*)d_in[10];
    const float* L2w = (const float*)d_in[11];
    const float* L2b = (const float*)d_in[12];
    const float* L3w = (const float*)d_in[13];
    const float* L3b = (const float*)d_in[14];
    float* out = (float*)d_out;

    const int n = N_NODES, E = N_EDGES;
    const int* src = ei;
    const int* dst = ei + E;

    // ---- workspace layout (bytes) ----
    char* wsb = (char*)d_ws;
    size_t off = 0;
    auto alloc = [&](size_t bytes) -> char* {
        char* p = wsb + off;
        off += (bytes + 255) & ~(size_t)255;
        return p;
    };
    float* dinv   = (float*)alloc(N_NODES * 4);
    int* rowptr   = (int*)alloc((N_NODES + 1) * 4);
    int* cursor   = (int*)alloc(N_NODES * 4);
    int* colb     = (int*)alloc((size_t)N_EDGES * 4);
    float* val    = (float*)alloc((size_t)N_EDGES * 4);
    int* bsums    = (int*)alloc(256 * 4);
    unsigned short* W1th = (unsigned short*)alloc(512 * 128 * 2);
    unsigned short* W1tl = (unsigned short*)alloc(512 * 128 * 2);
    unsigned short* W2th = (unsigned short*)alloc(256 * 512 * 2);
    unsigned short* W2tl = (unsigned short*)alloc(256 * 512 * 2);
    unsigned short* W3th = (unsigned short*)alloc(128 * 256 * 2);
    unsigned short* W3tl = (unsigned short*)alloc(128 * 256 * 2);
    unsigned short* aggXh = (unsigned short*)alloc((size_t)M_PAD * 128 * 2);  // pool A
    unsigned short* aggXl = (unsigned short*)alloc((size_t)M_PAD * 128 * 2);
    unsigned short* h1h  = (unsigned short*)alloc((size_t)M_PAD * 512 * 2);   // pool B1
    unsigned short* h1l  = (unsigned short*)alloc((size_t)M_PAD * 512 * 2);   // pool B2
    float* t2     = (float*)alloc((size_t)M_PAD * 256 * 4);
    // aliases (lifetimes disjoint):
    unsigned short* agg2h = aggXh;                                   // aggX dead after GEMM L1 (25.6MB = both aggX planes)
    unsigned short* agg2l = (unsigned short*)h1h;                    // h1 dead after GEMM L2 (first half of h1h)
    float* t3   = (float*)((char*)h1h + (size_t)M_PAD * 256 * 2);    // second half of h1h
    float* agg3 = (float*)h1l;                                       // first 25.6MB of h1l

    const int nb = (n + 511) / 512;
    const int gshard = 8 * 1024;  // 8 slices x 1024 node-blocks; ~12 nodes/wave

    // deg + CSR count (one pass)
    hipMemsetAsync(dinv, 0, n * sizeof(float), stream);
    hipMemsetAsync(cursor, 0, n * sizeof(int), stream);
    degcnt_kernel<<<(E + 255) / 256, 256, 0, stream>>>(dst, ew, dinv, cursor, E);
    dinv_kernel<<<(n + 255) / 256, 256, 0, stream>>>(dinv, n);

    // weight transpose+split (independent, cheap)
    wsplit_kernel<<<(128 * 512 + 255) / 256, 256, 0, stream>>>(W1, W1th, W1tl, 128, 512);
    wsplit_kernel<<<(512 * 256 + 255) / 256, 256, 0, stream>>>(W2, W2th, W2tl, 512, 256);
    wsplit_kernel<<<(256 * 128 + 255) / 256, 256, 0, stream>>>(W3, W3th, W3tl, 256, 128);

    // CSR build (by dst)
    scan_block_kernel<<<nb, 512, 0, stream>>>(cursor, rowptr, bsums, n);
    scan_sums_kernel<<<1, 64, 0, stream>>>(bsums, nb);
    scan_add_kernel<<<nb, 512, 0, stream>>>(rowptr, bsums, n);
    hipMemcpyAsync(cursor, rowptr, n * sizeof(int), hipMemcpyDeviceToDevice, stream);
    fill_kernel<<<(E + 255) / 256, 256, 0, stream>>>(src, dst, ew, dinv, cursor, colb, val, E);

    // ----- layer 1: aggX = A_hat x (split) ; h1 = split(relu(aggX@W1 + b1))
    gather_shard<128, false, false, true><<<gshard, 256, 0, stream>>>(
        x, rowptr, colb, val, dinv, nullptr, nullptr, aggXh, aggXl, n);
    {
        dim3 g(M_PAD / 128, 512 / 128);
        mfma_gemm<1><<<g, 256, 0, stream>>>(aggXh, aggXl, W1th, W1tl, b1, nullptr, h1h, h1l, 128, 512);
    }
    // ----- layer 2: t2 = h1 @ W2 (f32) ; agg2 = split(relu(A_hat t2 + b2))
    {
        dim3 g(M_PAD / 128, 256 / 128);
        mfma_gemm<0><<<g, 256, 0, stream>>>(h1h, h1l, W2th, W2tl, nullptr, t2, nullptr, nullptr, 512, 256);
    }
    gather_shard<256, true, true, true><<<gshard, 256, 0, stream>>>(
        t2, rowptr, colb, val, dinv, b2, nullptr, agg2h, agg2l, n);
    // ----- layer 3: t3 = relu(agg2) @ W3 (f32) ; agg3 = A_hat t3 + b3 (f32)
    {
        dim3 g(M_PAD / 128, 128 / 128);
        mfma_gemm<0><<<g, 256, 0, stream>>>(agg2h, agg2l, W3th, W3tl, nullptr, t3, nullptr, nullptr, 256, 128);
    }
    gather_shard<128, true, false, false><<<gshard, 256, 0, stream>>>(
        t3, rowptr, colb, val, dinv, b3, agg3, nullptr, nullptr, n);
    // ----- MLP head + softmax
    mlp_kernel<<<1024, 256, 0, stream>>>(agg3, L1w, L1b, L2w, L2b, L3w, L3b, out, n);
}